// Round 4
// baseline (51.368 us; speedup 1.0000x reference)
//
#include <hip/hip_runtime.h>
#include <math.h>

#define NQ 10
#define DIM 1024
#define HID 64
#define NT 256

template<int CTRL>
__device__ __forceinline__ float fdpp(float v) {
    return __int_as_float(__builtin_amdgcn_update_dpp(
        0, __float_as_int(v), CTRL, 0xF, 0xF, true));
}
__device__ __forceinline__ float bperm(int a4, float v) {
    return __int_as_float(__builtin_amdgcn_ds_bpermute(a4, __float_as_int(v)));
}

// fused RY*RX 2x2 complex gate: (r0,i0)=bit-0 element, (r1,i1)=bit-1 element
__device__ __forceinline__ void l1pair(float4 g, float& r0, float& i0, float& r1, float& i1) {
    float n0r = g.x * r0 - g.y * i0 - g.z * r1 + g.w * i1;
    float n0i = g.x * i0 + g.y * r0 - g.z * i1 - g.w * r1;
    float n1r = g.z * r0 + g.w * i0 + g.x * r1 + g.y * i1;
    float n1i = g.z * i0 - g.w * r0 + g.x * i1 - g.y * r1;
    r0 = n0r; i0 = n0i; r1 = n1r; i1 = n1i;
}
__device__ __forceinline__ void l2pair(float2 g, float& r0, float& i0, float& r1, float& i1) {
    float n0r = g.x * r0 - g.y * r1, n0i = g.x * i0 - g.y * i1;
    float n1r = g.y * r0 + g.x * r1, n1i = g.y * i0 + g.x * i1;
    r0 = n0r; i0 = n0i; r1 = n1r; i1 = n1i;
}

// layer-1 gate on lane-bit P (element bit P), shuffle/DPP form
template<int P>
__device__ __forceinline__ void lane_gate_l1(float4 g, int lane, float (&vr)[16], float (&vi)[16]) {
    const float fsb = ((lane >> P) & 1) ? 1.f : -1.f;
    const float Bs = fsb * g.y, Cs = fsb * g.z;
    const int a4 = (lane ^ (1 << P)) << 2;
    #pragma unroll
    for (int r = 0; r < 16; r++) {
        float ur, ui;
        if constexpr (P == 0)      { ur = fdpp<0xB1>(vr[r]); ui = fdpp<0xB1>(vi[r]); }
        else if constexpr (P == 1) { ur = fdpp<0x4E>(vr[r]); ui = fdpp<0x4E>(vi[r]); }
        else                       { ur = bperm(a4, vr[r]);  ui = bperm(a4, vi[r]); }
        float nr = g.x * vr[r] + Bs * vi[r] + Cs * ur + g.w * ui;
        float ni = g.x * vi[r] - Bs * vr[r] + Cs * ui - g.w * ur;
        vr[r] = nr; vi[r] = ni;
    }
}
template<int P>
__device__ __forceinline__ void lane_gate_l2(float2 g, int lane, float (&vr)[16], float (&vi)[16]) {
    const float fsb = ((lane >> P) & 1) ? 1.f : -1.f;
    const float ssf = fsb * g.y;
    const int a4 = (lane ^ (1 << P)) << 2;
    #pragma unroll
    for (int r = 0; r < 16; r++) {
        float ur, ui;
        if constexpr (P == 0)      { ur = fdpp<0xB1>(vr[r]); ui = fdpp<0xB1>(vi[r]); }
        else if constexpr (P == 1) { ur = fdpp<0x4E>(vr[r]); ui = fdpp<0x4E>(vi[r]); }
        else                       { ur = bperm(a4, vr[r]);  ui = bperm(a4, vi[r]); }
        vr[r] = g.x * vr[r] + ssf * ur;
        vi[r] = g.x * vi[r] + ssf * ui;
    }
}

// obs partial sum, half-set on reg-bit HB (xm high part nonzero)
template<int HB>
__device__ __forceinline__ float reghalf_sum(const float (&vr)[16], const float (&vi)[16],
                                             const float2* st, int pbase, int xh, int w1, int cm) {
    float acc = 0.f;
    #pragma unroll
    for (int r = 0; r < 16; r++) {
        if (((r >> HB) & 1) == 0) {
            float2 c = st[pbase | ((r ^ xh) << 6)];
            float crr = cm ? c.y : c.x;
            float cii = cm ? __int_as_float(__float_as_int(c.x) ^ 0x80000000) : c.y;
            float t = vr[r] * crr + vi[r] * cii;
            float cf = __int_as_float(0x40000000 | (((w1 >> r) & 1) << 31));
            acc = fmaf(cf, t, acc);
        }
    }
    return acc;
}

__global__ __launch_bounds__(NT, 2) void qsa_kernel(
    const float* __restrict__ x,
    const float* __restrict__ rx0,
    const float* __restrict__ ry0,
    const float* __restrict__ ry1,
    const int*   __restrict__ op_codes,
    float* __restrict__ out,
    int rows)
{
    __shared__ float2 st[4 * DIM];          // per-wave private 8KB slices
    __shared__ float4 s_l1[NQ];
    __shared__ float2 s_l2[NQ];
    __shared__ int4   s_meta[HID];          // xm, yzm, w1, mode|hb<<2|cm<<5

    const int tid  = threadIdx.x;
    const int lane = tid & 63;
    const int wave = tid >> 6;
    const int row  = blockIdx.x * 4 + wave;
    const bool active = row < rows;
    const int wbase = wave << 10;

    // ---- setup tables (block-shared) ----
    if (tid < NQ) {
        float a = 0.5f * rx0[tid], b = 0.5f * ry0[tid];
        float c1 = cosf(a), s1 = sinf(a), c2 = cosf(b), s2 = sinf(b);
        s_l1[tid] = make_float4(c1 * c2, s1 * s2, s2 * c1, c2 * s1);  // A,B,C,D
    } else if (tid < 2 * NQ) {
        float a = 0.5f * ry1[tid - NQ];
        s_l2[tid - NQ] = make_float2(cosf(a), sinf(a));
    }
    if (tid >= 64 && tid < 64 + HID) {
        const int o = tid - 64;
        int xm = 0, yzm = 0, ny = 0;
        #pragma unroll
        for (int q = 0; q < NQ; q++) {
            int code = op_codes[o * NQ + q];
            int bit  = 1 << (NQ - 1 - q);       // qubit q = element bit 9-q
            if (code == 1) xm |= bit;
            else if (code == 2) { xm |= bit; yzm |= bit; ny++; }
            else if (code == 3) yzm |= bit;
        }
        const int cm = ny & 1, gflip = (ny >> 1) & 1;
        const int yh = yzm >> 6;
        int w1 = 0;
        #pragma unroll
        for (int r = 0; r < 16; r++)
            w1 |= ((__popc(r & yh) & 1) ^ gflip) << r;
        int mode, hb;
        if (xm == 0)            { mode = 0; hb = 0; }
        else if ((xm >> 6) != 0){ mode = 1; hb = __ffs(xm >> 6) - 1; }
        else                    { mode = 2; hb = __ffs(xm) - 1; }
        s_meta[o] = make_int4(xm, yzm, w1, mode | (hb << 2) | (cm << 5));
    }

    // ---- load + normalize (pre-barrier, no LDS use) ----
    float vr[16], vi[16];
    if (active) {
        const float* xr = x + (size_t)row * DIM;
        float ssq = 0.f;
        #pragma unroll
        for (int r = 0; r < 16; r++) {
            vr[r] = xr[(r << 6) + lane];
            vi[r] = 0.f;
            ssq += vr[r] * vr[r];
        }
        #pragma unroll
        for (int off = 32; off; off >>= 1) ssq += __shfl_xor(ssq, off, 64);
        const float inv = 1.0f / sqrtf(ssq);
        #pragma unroll
        for (int r = 0; r < 16; r++) vr[r] *= inv;
    }

    __syncthreads();            // the only barrier: publish tables
    if (!active) return;

    // ---- layer 1: qubits 0..3 on reg-bits 3..0 (free), 4..9 on lane-bits 5..0 ----
    #pragma unroll
    for (int j = 0; j < 4; j++) {
        const float4 g = s_l1[j];
        const int m = 1 << (3 - j);
        #pragma unroll
        for (int r = 0; r < 16; r++)
            if (!(r & m)) l1pair(g, vr[r], vi[r], vr[r | m], vi[r | m]);
    }
    lane_gate_l1<5>(s_l1[4], lane, vr, vi);
    lane_gate_l1<4>(s_l1[5], lane, vr, vi);
    lane_gate_l1<3>(s_l1[6], lane, vr, vi);
    lane_gate_l1<2>(s_l1[7], lane, vr, vi);
    lane_gate_l1<1>(s_l1[8], lane, vr, vi);
    lane_gate_l1<0>(s_l1[9], lane, vr, vi);

    // ---- CNOT ring: composed permutation gather (wave-private LDS slice) ----
    #pragma unroll
    for (int r = 0; r < 16; r++) st[wbase | (r << 6) | lane] = make_float2(vr[r], vi[r]);
    #pragma unroll
    for (int r = 0; r < 16; r++) {
        int d = (r << 6) | lane;
        int src = (d ^ (d >> 1)) ^ ((d & 1) * 0x300);
        float2 t = st[wbase | src];
        vr[r] = t.x; vi[r] = t.y;
    }

    // ---- layer 2 (RY) ----
    #pragma unroll
    for (int j = 0; j < 4; j++) {
        const float2 g = s_l2[j];
        const int m = 1 << (3 - j);
        #pragma unroll
        for (int r = 0; r < 16; r++)
            if (!(r & m)) l2pair(g, vr[r], vi[r], vr[r | m], vi[r | m]);
    }
    lane_gate_l2<5>(s_l2[4], lane, vr, vi);
    lane_gate_l2<4>(s_l2[5], lane, vr, vi);
    lane_gate_l2<3>(s_l2[6], lane, vr, vi);
    lane_gate_l2<2>(s_l2[7], lane, vr, vi);
    lane_gate_l2<1>(s_l2[8], lane, vr, vi);
    lane_gate_l2<0>(s_l2[9], lane, vr, vi);

    // ---- mirror for c-side gathers ----
    #pragma unroll
    for (int r = 0; r < 16; r++) st[wbase | (r << 6) | lane] = make_float2(vr[r], vi[r]);

    // ---- observables: a-side = registers, c-side = wave-private LDS ----
    float res = 0.f;
    #pragma unroll 1
    for (int o = 0; o < HID; o++) {
        int4 mt = s_meta[o];
        const int xm   = __builtin_amdgcn_readfirstlane(mt.x);
        const int yzm  = __builtin_amdgcn_readfirstlane(mt.y);
        const int w1   = __builtin_amdgcn_readfirstlane(mt.z);
        const int fl   = __builtin_amdgcn_readfirstlane(mt.w);
        const int mode = fl & 3, hb = (fl >> 2) & 7, cm = (fl >> 5) & 1;
        const int xl = xm & 63, xh = xm >> 6;
        const int sl = __popc(lane & yzm & 63) & 1;
        float acc = 0.f;
        if (mode == 0) {                         // diagonal: pure Z/I
            #pragma unroll
            for (int r = 0; r < 16; r++) {
                float t = vr[r] * vr[r] + vi[r] * vi[r];
                float cf = __int_as_float(0x3F800000 | (((w1 >> r) & 1) << 31));
                acc = fmaf(cf, t, acc);
            }
        } else if (mode == 1) {                  // half-set on a reg bit
            const int pbase = wbase | (lane ^ xl);
            switch (hb) {
                case 0: acc = reghalf_sum<0>(vr, vi, st, pbase, xh, w1, cm); break;
                case 1: acc = reghalf_sum<1>(vr, vi, st, pbase, xh, w1, cm); break;
                case 2: acc = reghalf_sum<2>(vr, vi, st, pbase, xh, w1, cm); break;
                default: acc = reghalf_sum<3>(vr, vi, st, pbase, xh, w1, cm); break;
            }
        } else {                                 // half-set on a lane bit (xm>>6==0)
            if (((lane >> hb) & 1) == 0) {
                const int pbase = wbase | (lane ^ xl);
                #pragma unroll
                for (int r = 0; r < 16; r++) {
                    float2 c = st[pbase | (r << 6)];
                    float crr = cm ? c.y : c.x;
                    float cii = cm ? __int_as_float(__float_as_int(c.x) ^ 0x80000000) : c.y;
                    float t = vr[r] * crr + vi[r] * cii;
                    float cf = __int_as_float(0x40000000 | (((w1 >> r) & 1) << 31));
                    acc = fmaf(cf, t, acc);
                }
            }
        }
        // lane part of the Pauli sign
        acc = __int_as_float(__float_as_int(acc) ^ (sl << 31));
        // ---- XOR-butterfly reduction: ALL lanes end with the 64-lane sum ----
        // (row_shr-style was wrong: it accumulates toward lane 63, not lane 0)
        acc += fdpp<0xB1>(acc);                  // xor 1  (quad_perm [1,0,3,2])
        acc += fdpp<0x4E>(acc);                  // xor 2  (quad_perm [2,3,0,1])
        acc += fdpp<0x141>(acc);                 // row_half_mirror = lane^7 ≡ xor 4 (grp-4 uniform)
        acc += fdpp<0x140>(acc);                 // row_mirror      = lane^15 ≡ xor 8 (grp-8 uniform)
        acc += __shfl_xor(acc, 16, 64);          // xor 16
        acc += __shfl_xor(acc, 32, 64);          // xor 32
        if (lane == o) res = acc;
    }
    out[(size_t)row * HID + lane] = res;
}

extern "C" void kernel_launch(void* const* d_in, const int* in_sizes, int n_in,
                              void* d_out, int out_size, void* d_ws, size_t ws_size,
                              hipStream_t stream) {
    const float* x   = (const float*)d_in[0];
    const float* rx0 = (const float*)d_in[1];
    const float* ry0 = (const float*)d_in[2];
    const float* ry1 = (const float*)d_in[3];
    const int*   op  = (const int*)d_in[4];
    float* o = (float*)d_out;
    const int rows = in_sizes[0] / DIM;    // B*T = 2048
    qsa_kernel<<<(rows + 3) / 4, NT, 0, stream>>>(x, rx0, ry0, ry1, op, o, rows);
}